// Round 13
// baseline (2007.234 us; speedup 1.0000x reference)
//
#include <hip/hip_runtime.h>
#include <hip/hip_fp16.h>
#include <math.h>

#define TT 833          // output timesteps
#define GDIM 1024       // 4*H gates

typedef _Float16 f16x8 __attribute__((ext_vector_type(8)));
typedef float    f32x4 __attribute__((ext_vector_type(4)));

__device__ __forceinline__ float sigm(float x){ return 1.f/(1.f+__expf(-x)); }

#if __has_builtin(__builtin_amdgcn_sdot4)
__device__ __forceinline__ int sdot4(unsigned a, unsigned b, int c){
  return __builtin_amdgcn_sdot4((int)a, (int)b, c, false);
}
#else
__device__ __forceinline__ int sdot4(unsigned a, unsigned b, int c){
  int ai = (int)a, bi = (int)b;
  c += ((ai<<24)>>24)*((bi<<24)>>24);
  c += ((ai<<16)>>24)*((bi<<16)>>24);
  c += ((ai<<8)>>24)*((bi<<8)>>24);
  c += (ai>>24)*(bi>>24);
  return c;
}
#endif

// Gate-row permutation: new row t <-> old row (t&3)*256 + (t>>2).
// Puts cell j's gates {i,f,g,o} in adjacent lanes 4j..4j+3 (same wave) so the
// LSTM cell update needs only intra-wave shuffles -> 1 barrier/step instead of 2.

// ---------------- level smoothing scan ----------------
__global__ void levels_k(const float* __restrict__ train, const float* __restrict__ ism,
                         float* __restrict__ levs){
  int b = threadIdx.x;
  if (b >= 32) return;
  float a = 1.f/(1.f+expf(-ism[0]));
  const float* tr = train + b*1024;
  float* lv = levs + b*1024;
  float lev = fmaxf(tr[0], 0.1f);
  lv[0] = lev;
  for (int t = 1; t < 1024; ++t){
    lev = fmaxf(a*tr[t] + (1.f-a)*lev, 0.1f);
    lv[t] = lev;
  }
}

// ---------------- normalized input windows x0[t*32+b][168] ----------------
__global__ void win_x_k(const float* __restrict__ train, const float* __restrict__ levs,
                        float* __restrict__ x0){
  int idx = blockIdx.x*256 + threadIdx.x;   // exactly 833*32*168
  int i = idx % 168;
  int r = idx / 168;       // t*32+b
  int b = r & 31;
  int t = r >> 5;
  x0[idx] = train[b*1024 + t + i] / levs[b*1024 + t + 167];
}

// ---------------- out_win -> d_out second half ----------------
__global__ void win_out_k(const float* __restrict__ train, const float* __restrict__ levs,
                          float* __restrict__ ow){
  int idx = blockIdx.x*256 + threadIdx.x;   // exactly 833*32*24
  int o = idx % 24;
  int r = idx / 24;
  int b = r & 31;
  int t = r >> 5;
  ow[idx] = train[b*1024 + 168 + t + o] / levs[b*1024 + t + 167];
}

// ---------------- permute wih rows + fuse biases (one-time) ----------------
__global__ void permw_k(const float* __restrict__ wih, const float* __restrict__ bih,
                        const float* __restrict__ bhh, float* __restrict__ wP,
                        float* __restrict__ bP, int K){
  int t = blockIdx.x;                       // 1024 rows
  int g = ((t & 3) << 8) + (t >> 2);
  for (int k = threadIdx.x; k < K; k += 256)
    wP[(size_t)t*K + k] = wih[(size_t)g*K + k];
  if (threadIdx.x == 0) bP[t] = bih[g] + bhh[g];
}

// ---------------- quantize whh -> int8 wq[k16][1024] permuted rows (+ scale) ----------------
__global__ void packq_k(const float* __restrict__ w, uint4* __restrict__ wq,
                        float* __restrict__ sc){
  int t = blockIdx.x*256 + threadIdx.x;     // 1024 rows
  if (t >= 1024) return;
  int g = ((t & 3) << 8) + (t >> 2);
  const float* row = w + (size_t)g*256;
  float amax = 0.f;
  for (int k = 0; k < 256; ++k) amax = fmaxf(amax, fabsf(row[k]));
  amax = fmaxf(amax, 1e-20f);
  float s = amax/127.f, inv = 127.f/amax;
  sc[t] = s;
  for (int k16 = 0; k16 < 16; ++k16){
    union { uint4 u; signed char b[16]; } r;
    #pragma unroll
    for (int j = 0; j < 16; ++j){
      float q = rintf(row[k16*16 + j]*inv);
      q = fminf(fmaxf(q, -127.f), 127.f);
      r.b[j] = (signed char)q;
    }
    wq[(size_t)k16*1024 + t] = r.u;
  }
}

// ---------------- MFMA fp16 GEMM: C[m][n] = A[map(m)][:K] . W[n][:K] + b1 (+b2), opt tanh ----
// 128x128 tile, 4 waves (2x2), mfma_f32_16x16x32_f16, 4x4 frags/wave, BK=32.
// outHalf: store C as __half (used for the G gate buffer).
__global__ __launch_bounds__(256) void proj_mfma(
    const float* __restrict__ A, const float* __restrict__ W,
    const float* __restrict__ b1, const float* __restrict__ b2,
    float* __restrict__ C, int Mout, int K, int N, int dil, int act, int outHalf)
{
  __shared__ _Float16 As[128*40];
  __shared__ _Float16 Bs[128*40];
  const int tid = threadIdx.x;
  const int lane = tid & 63;
  const int w = tid >> 6, wr = w >> 1, wc = w & 1;
  const int m0 = blockIdx.y << 7, n0 = blockIdx.x << 7;

  const int rowA = tid >> 1;
  int srcrow;
  {
    int m = m0 + rowA;
    if (dil == 0) srcrow = (m < Mout) ? m : -1;
    else {
      int rows = dil << 5;
      int j = m / rows;
      int q = m - j*rows;
      int t = j*dil + (q >> 5);
      srcrow = (t < TT) ? ((t << 5) + (q & 31)) : -1;
    }
  }
  const int halfsel = tid & 1;
  const int nrow = n0 + rowA;

  f32x4 acc[4][4];
  #pragma unroll
  for (int i = 0; i < 4; ++i)
    #pragma unroll
    for (int j = 0; j < 4; ++j) acc[i][j] = (f32x4){0.f,0.f,0.f,0.f};

  const int nkt = (K + 31) >> 5;
  for (int kt = 0; kt < nkt; ++kt){
    const int k0 = (kt << 5) + halfsel*16;
    {
      union { uint4 u[2]; _Float16 h[16]; } tmp;
      if (srcrow >= 0 && k0 + 16 <= K){
        const float* s = A + (size_t)srcrow*K + k0;
        #pragma unroll
        for (int j = 0; j < 4; ++j){
          float4 v = *reinterpret_cast<const float4*>(s + j*4);
          tmp.h[j*4+0]=(_Float16)v.x; tmp.h[j*4+1]=(_Float16)v.y;
          tmp.h[j*4+2]=(_Float16)v.z; tmp.h[j*4+3]=(_Float16)v.w;
        }
      } else {
        const float* s = (srcrow >= 0) ? A + (size_t)srcrow*K : nullptr;
        #pragma unroll
        for (int j = 0; j < 16; ++j){
          int kk = k0 + j;
          tmp.h[j] = (s && kk < K) ? (_Float16)s[kk] : (_Float16)0.f;
        }
      }
      uint4* dst = reinterpret_cast<uint4*>(&As[rowA*40 + halfsel*16]);
      dst[0] = tmp.u[0]; dst[1] = tmp.u[1];
    }
    {
      union { uint4 u[2]; _Float16 h[16]; } tmp;
      if (k0 + 16 <= K){
        const float* s = W + (size_t)nrow*K + k0;
        #pragma unroll
        for (int j = 0; j < 4; ++j){
          float4 v = *reinterpret_cast<const float4*>(s + j*4);
          tmp.h[j*4+0]=(_Float16)v.x; tmp.h[j*4+1]=(_Float16)v.y;
          tmp.h[j*4+2]=(_Float16)v.z; tmp.h[j*4+3]=(_Float16)v.w;
        }
      } else {
        const float* s = W + (size_t)nrow*K;
        #pragma unroll
        for (int j = 0; j < 16; ++j){
          int kk = k0 + j;
          tmp.h[j] = (kk < K) ? (_Float16)s[kk] : (_Float16)0.f;
        }
      }
      uint4* dst = reinterpret_cast<uint4*>(&Bs[rowA*40 + halfsel*16]);
      dst[0] = tmp.u[0]; dst[1] = tmp.u[1];
    }
    __syncthreads();
    {
      const int kg = lane >> 4, r16 = lane & 15;
      f16x8 af[4], bf[4];
      #pragma unroll
      for (int mi = 0; mi < 4; ++mi)
        af[mi] = *reinterpret_cast<const f16x8*>(&As[(wr*64 + mi*16 + r16)*40 + kg*8]);
      #pragma unroll
      for (int nj = 0; nj < 4; ++nj)
        bf[nj] = *reinterpret_cast<const f16x8*>(&Bs[(wc*64 + nj*16 + r16)*40 + kg*8]);
      #pragma unroll
      for (int mi = 0; mi < 4; ++mi)
        #pragma unroll
        for (int nj = 0; nj < 4; ++nj)
          acc[mi][nj] = __builtin_amdgcn_mfma_f32_16x16x32_f16(af[mi], bf[nj], acc[mi][nj], 0, 0, 0);
    }
    __syncthreads();
  }
  #pragma unroll
  for (int mi = 0; mi < 4; ++mi){
    #pragma unroll
    for (int p = 0; p < 4; ++p){
      int mrow = m0 + wr*64 + mi*16 + (lane >> 4)*4 + p;
      if (mrow >= Mout) continue;
      #pragma unroll
      for (int nj = 0; nj < 4; ++nj){
        int ncol = n0 + wc*64 + nj*16 + (lane & 15);
        float v = acc[mi][nj][p] + b1[ncol] + (b2 ? b2[ncol] : 0.f);
        if (act) v = tanhf(v);
        if (outHalf) reinterpret_cast<__half*>(C)[(size_t)mrow*N + ncol] = __float2half(v);
        else C[(size_t)mrow*N + ncol] = v;
      }
    }
  }
}

// ---------------- register-weight int8 sdot4 LSTM, permuted gates, 1 barrier/step ----------
// Thread t owns permuted gate row t = gate (t&3) of cell (t>>2). Cell update is
// intra-wave: 4 shfl gather the gates, c lives redundantly in regs of the 4 lanes,
// lane (t&3)==0 writes h (int8 to double-buffered hq + fp32 to out).
template<int NR>
__global__ __launch_bounds__(1024) void srecr_k(
    const uint4* __restrict__ wq, const float* __restrict__ scale,
    const __half* __restrict__ Gin,
    float* __restrict__ out, const float* __restrict__ res,
    int nsteps, int d, int rowsTotal)
{
  __shared__ __align__(16) unsigned int hq[2][NR][64];
  const int tid = threadIdx.x;
  const int lane = tid & 63;
  const int base = lane & ~3;
  const int kg = tid & 3;           // gate index (2 == g -> tanh)
  const int j = tid >> 2;           // cell index
  const int q0 = blockIdx.x*NR;
  const float sg = scale[tid]*(1.f/127.f);
  uint4 wr_[16];
  #pragma unroll
  for (int kk = 0; kk < 16; ++kk) wr_[kk] = wq[(size_t)kk*1024 + tid];
  float c[NR];
  #pragma unroll
  for (int rr = 0; rr < NR; ++rr) c[rr] = 0.f;
  for (int e = tid; e < 2*NR*64; e += 1024) (&hq[0][0][0])[e] = 0u;
  __syncthreads();

  for (int step = 0; step < nsteps; ++step){
    const int cur = step & 1;
    float gin[NR];
    const __half* gbase = Gin + ((size_t)step*rowsTotal + q0)*GDIM;
    #pragma unroll
    for (int rr = 0; rr < NR; ++rr) gin[rr] = __half2float(gbase[rr*GDIM + tid]);
    #pragma unroll
    for (int rr = 0; rr < NR; ++rr){
      int a0 = 0, a1 = 0;
      #pragma unroll
      for (int k16 = 0; k16 < 8; ++k16){
        uint4 h4 = *reinterpret_cast<const uint4*>(&hq[cur][rr][4*k16]);
        uint4 w = wr_[k16];
        a0 = sdot4(w.x, h4.x, a0); a0 = sdot4(w.y, h4.y, a0);
        a0 = sdot4(w.z, h4.z, a0); a0 = sdot4(w.w, h4.w, a0);
        uint4 h4b = *reinterpret_cast<const uint4*>(&hq[cur][rr][4*(k16+8)]);
        uint4 wb = wr_[k16+8];
        a1 = sdot4(wb.x, h4b.x, a1); a1 = sdot4(wb.y, h4b.y, a1);
        a1 = sdot4(wb.z, h4b.z, a1); a1 = sdot4(wb.w, h4b.w, a1);
      }
      float p = fmaf((float)(a0 + a1), sg, gin[rr]);
      // gate activation: sigm for i,f,o; tanh for g via 2*sigm(2p)-1 (branchless)
      float px = (kg == 2) ? p + p : p;
      float s = 1.f/(1.f + __expf(-px));
      float a = (kg == 2) ? fmaf(2.f, s, -1.f) : s;
      float iv = __shfl(a, base + 0);
      float fv = __shfl(a, base + 1);
      float gv = __shfl(a, base + 2);
      float ov = __shfl(a, base + 3);
      float cn = fmaf(fv, c[rr], iv*gv);
      c[rr] = cn;
      float e2 = __expf(-2.f*cn);
      float h = ov*(1.f - e2)/(1.f + e2);
      if (kg == 0){
        int qh = (int)rintf(h*127.f);
        reinterpret_cast<signed char*>(&hq[cur^1][rr][0])[j] = (signed char)qh;
        int q = q0 + rr;
        int tg = step*d + (q >> 5);
        if (tg < TT){
          size_t oi = ((size_t)tg*32 + (q & 31))*256 + j;
          out[oi] = res ? (h + res[oi]) : h;
        }
      }
    }
    __syncthreads();
  }
}

// ---------------- streamed-weight variant (NR=8, d=64) — same structure ----------------
template<int NR>
__global__ __launch_bounds__(1024) void srecq_k(
    const uint4* __restrict__ wq, const float* __restrict__ scale,
    const __half* __restrict__ Gin,
    float* __restrict__ out, const float* __restrict__ res,
    int nsteps, int d, int rowsTotal)
{
  __shared__ __align__(16) unsigned int hq[2][NR][64];
  const int tid = threadIdx.x;
  const int lane = tid & 63;
  const int base = lane & ~3;
  const int kg = tid & 3;
  const int j = tid >> 2;
  const int q0 = blockIdx.x*NR;
  const float sg = scale[tid]*(1.f/127.f);
  float c[NR];
  #pragma unroll
  for (int rr = 0; rr < NR; ++rr) c[rr] = 0.f;
  for (int e = tid; e < 2*NR*64; e += 1024) (&hq[0][0][0])[e] = 0u;
  __syncthreads();

  for (int step = 0; step < nsteps; ++step){
    const int cur = step & 1;
    float gin[NR];
    const __half* gbase = Gin + ((size_t)step*rowsTotal + q0)*GDIM;
    #pragma unroll
    for (int rr = 0; rr < NR; ++rr) gin[rr] = __half2float(gbase[rr*GDIM + tid]);
    int acc[NR];
    #pragma unroll
    for (int rr = 0; rr < NR; ++rr) acc[rr] = 0;
    #pragma unroll 4
    for (int k16 = 0; k16 < 16; ++k16){
      uint4 w = wq[(size_t)k16*1024 + tid];
      #pragma unroll
      for (int rr = 0; rr < NR; ++rr){
        uint4 h4 = *reinterpret_cast<const uint4*>(&hq[cur][rr][4*k16]);
        acc[rr] = sdot4(w.x, h4.x, acc[rr]);
        acc[rr] = sdot4(w.y, h4.y, acc[rr]);
        acc[rr] = sdot4(w.z, h4.z, acc[rr]);
        acc[rr] = sdot4(w.w, h4.w, acc[rr]);
      }
    }
    #pragma unroll
    for (int rr = 0; rr < NR; ++rr){
      float p = fmaf((float)acc[rr], sg, gin[rr]);
      float px = (kg == 2) ? p + p : p;
      float s = 1.f/(1.f + __expf(-px));
      float a = (kg == 2) ? fmaf(2.f, s, -1.f) : s;
      float iv = __shfl(a, base + 0);
      float fv = __shfl(a, base + 1);
      float gv = __shfl(a, base + 2);
      float ov = __shfl(a, base + 3);
      float cn = fmaf(fv, c[rr], iv*gv);
      c[rr] = cn;
      float e2 = __expf(-2.f*cn);
      float h = ov*(1.f - e2)/(1.f + e2);
      if (kg == 0){
        int qh = (int)rintf(h*127.f);
        reinterpret_cast<signed char*>(&hq[cur^1][rr][0])[j] = (signed char)qh;
        int q = q0 + rr;
        int tg = step*d + (q >> 5);
        if (tg < TT){
          size_t oi = ((size_t)tg*32 + (q & 31))*256 + j;
          out[oi] = res ? (h + res[oi]) : h;
        }
      }
    }
    __syncthreads();
  }
}

// ---------------- scoring head: pred[m][24] = xt[m][:] . sc_w[n][:] + sc_b ----------------
__global__ __launch_bounds__(256) void sc_head(const float* __restrict__ xt, const float* __restrict__ w,
                        const float* __restrict__ bias, float* __restrict__ outp, int M){
  __shared__ float arow[8][256];
  int m0 = blockIdx.x << 3;
  int tid = threadIdx.x;
  #pragma unroll
  for (int i = 0; i < 8; ++i){
    int e = tid + (i << 8);
    int r = e >> 8, k = e & 255;
    arow[r][k] = (m0 + r < M) ? xt[(size_t)(m0 + r)*256 + k] : 0.f;
  }
  __syncthreads();
  int r = tid >> 5, n = tid & 31;
  if (n < 24 && (m0 + r) < M){
    float acc = bias[n];
    const float* wr = w + n*256;
    #pragma unroll 8
    for (int k = 0; k < 256; ++k) acc = fmaf(arow[r][k], wr[k], acc);
    outp[(size_t)(m0 + r)*24 + n] = acc;
  }
}

extern "C" void kernel_launch(void* const* d_in, const int* in_sizes, int n_in,
                              void* d_out, int out_size, void* d_ws, size_t ws_size,
                              hipStream_t stream){
  const float* train = (const float*)d_in[0];
  const float* ism   = (const float*)d_in[4];
  const float* wih[4] = {(const float*)d_in[5], (const float*)d_in[9], (const float*)d_in[13], (const float*)d_in[17]};
  const float* whh[4] = {(const float*)d_in[6], (const float*)d_in[10], (const float*)d_in[14], (const float*)d_in[18]};
  const float* bih[4] = {(const float*)d_in[7], (const float*)d_in[11], (const float*)d_in[15], (const float*)d_in[19]};
  const float* bhh[4] = {(const float*)d_in[8], (const float*)d_in[12], (const float*)d_in[16], (const float*)d_in[20]};
  const float* nl_w = (const float*)d_in[21];
  const float* nl_b = (const float*)d_in[22];
  const float* sc_w = (const float*)d_in[23];
  const float* sc_b = (const float*)d_in[24];
  float* out = (float*)d_out;

  float* ws = (float*)d_ws;
  size_t off = 0;
  float* levs = ws + off;   off += 32768;
  uint4* wqk[4];
  for (int l = 0; l < 4; ++l){ wqk[l] = (uint4*)(ws + off); off += 65536; }   // 256KB each
  float* sck[4];
  for (int l = 0; l < 4; ++l){ sck[l] = ws + off; off += 1024; }
  float* wP[4];
  for (int l = 0; l < 4; ++l){ wP[l] = ws + off; off += 262144; }             // 1MB each
  float* bP[4];
  for (int l = 0; l < 4; ++l){ bP[l] = ws + off; off += 1024; }
  float* x0 = ws + off;     off += (size_t)26656*168;
  __half* G  = (__half*)(ws + off); off += (size_t)28672*1024/2;              // fp16 gates
  float* h0 = ws + off;     off += (size_t)26656*256;
  float* h1 = ws + off;     off += (size_t)26656*256;
  float* h2 = ws + off;     off += (size_t)26656*256;
  (void)ws_size; (void)in_sizes; (void)n_in; (void)out_size;

  levels_k<<<1, 64, 0, stream>>>(train, ism, levs);
  win_x_k<<<17493, 256, 0, stream>>>(train, levs, x0);
  win_out_k<<<2499, 256, 0, stream>>>(train, levs, out + 639744);
  const int Kin[4] = {168, 256, 256, 256};
  for (int l = 0; l < 4; ++l){
    packq_k<<<4, 256, 0, stream>>>(whh[l], wqk[l], sck[l]);
    permw_k<<<1024, 256, 0, stream>>>(wih[l], bih[l], bhh[l], wP[l], bP[l], Kin[l]);
  }

  // layer 0 (d=1): 833 steps, 32 rows -> 32 WGs x 1 row
  proj_mfma<<<dim3(8,209), 256, 0, stream>>>(x0, wP[0], bP[0], nullptr, (float*)G, 26656, 168, 1024, 0, 0, 1);
  srecr_k<1><<<32, 1024, 0, stream>>>(wqk[0], sck[0], G, h0, nullptr, 833, 1, 32);
  // layer 1 (d=4): 209 steps, 128 rows -> 128 WGs x 1 row
  proj_mfma<<<dim3(8,209), 256, 0, stream>>>(h0, wP[1], bP[1], nullptr, (float*)G, 26752, 256, 1024, 4, 0, 1);
  srecr_k<1><<<128, 1024, 0, stream>>>(wqk[1], sck[1], G, h1, nullptr, 209, 4, 128);
  // layer 2 (d=16): 53 steps, 512 rows -> 256 WGs x 2 rows
  proj_mfma<<<dim3(8,212), 256, 0, stream>>>(h1, wP[2], bP[2], nullptr, (float*)G, 27136, 256, 1024, 16, 0, 1);
  srecr_k<2><<<256, 1024, 0, stream>>>(wqk[2], sck[2], G, h2, nullptr, 53, 16, 512);
  // layer 3 (d=64): 14 steps, 2048 rows -> 256 WGs x 8 rows; residual h1; out overwrites h2
  proj_mfma<<<dim3(8,224), 256, 0, stream>>>(h2, wP[3], bP[3], nullptr, (float*)G, 28672, 256, 1024, 64, 0, 1);
  srecq_k<8><<<256, 1024, 0, stream>>>(wqk[3], sck[3], G, h2, h1, 14, 64, 2048);
  // nonlinear dense: xt = tanh(xf @ nl_w.T + nl_b)  (reuse h0)
  proj_mfma<<<dim3(2,209), 256, 0, stream>>>(h2, nl_w, nl_b, nullptr, h0, 26656, 256, 256, 0, 1, 0);
  // scoring head -> pred (first half of d_out)
  sc_head<<<3332, 256, 0, stream>>>(h0, sc_w, sc_b, out, 26656);
}